// Round 5
// baseline (121.145 us; speedup 1.0000x reference)
//
#include <hip/hip_runtime.h>

// WeightedMSELoss: loss = sum_i w(t_i) * (p_i - t_i)^2 / 31
// w(t) = 2^bin for t in (0.2*bin, 0.2*(bin+1)], bin in [0,5); else 0.
//
// R5: 4x oversubscribed grid (backfill for L3-hit/miss imbalance) +
// forced memory-level parallelism (full 8-load batch issued before any
// compute, pinned by sched_barrier).

typedef float f4 __attribute__((ext_vector_type(4)));

constexpr int kN = 33554432;               // 2**25 floats per array
constexpr int kBlock = 256;
constexpr int kBlocks = 8192;              // 4 fill-rounds of the machine
constexpr int kN4 = kN / 4;                // 2**23 float4
constexpr int kPerBlock = kN4 / kBlocks;   // 1024 float4 per block per array

__device__ __forceinline__ float contrib(float p, float t) {
    bool valid = (t > 0.0f) & (t <= 1.0f);
    int bin = (t > 0.2f) + (t > 0.4f) + (t > 0.6f) + (t > 0.8f);
    float d = p - t;
    float v = __builtin_ldexpf(d * d, bin);   // (p-t)^2 * 2^bin
    return valid ? v : 0.0f;
}

__device__ __forceinline__ float contrib4(f4 p, f4 t) {
    return contrib(p.x, t.x) + contrib(p.y, t.y) +
           contrib(p.z, t.z) + contrib(p.w, t.w);
}

__global__ __launch_bounds__(kBlock)
void wmse_kernel(const f4* __restrict__ p4,
                 const f4* __restrict__ t4,
                 float* __restrict__ out) {
    int tid = threadIdx.x;
    int base = blockIdx.x * kPerBlock + tid;

    // Issue ALL 8 independent 16B loads before any consumption.
    f4 p0 = p4[base];
    f4 p1 = p4[base + kBlock];
    f4 p2 = p4[base + 2 * kBlock];
    f4 p3 = p4[base + 3 * kBlock];
    f4 t0 = t4[base];
    f4 t1 = t4[base + kBlock];
    f4 t2 = t4[base + 2 * kBlock];
    f4 t3 = t4[base + 3 * kBlock];
    __builtin_amdgcn_sched_barrier(0);   // keep loads above compute

    float acc = contrib4(p0, t0);
    acc += contrib4(p1, t1);
    acc += contrib4(p2, t2);
    acc += contrib4(p3, t3);

    // wave-64 butterfly reduce
    #pragma unroll
    for (int off = 32; off > 0; off >>= 1)
        acc += __shfl_down(acc, off, 64);

    __shared__ float smem[kBlock / 64];
    int lane = tid & 63;
    int wid  = tid >> 6;
    if (lane == 0) smem[wid] = acc;
    __syncthreads();
    if (tid == 0) {
        float b = 0.0f;
        #pragma unroll
        for (int w = 0; w < kBlock / 64; ++w) b += smem[w];
        atomicAdd(out, b * (1.0f / 31.0f));
    }
}

extern "C" void kernel_launch(void* const* d_in, const int* in_sizes, int n_in,
                              void* d_out, int out_size, void* d_ws, size_t ws_size,
                              hipStream_t stream) {
    const f4* predicted = (const f4*)d_in[0];
    const f4* target    = (const f4*)d_in[1];
    float* out = (float*)d_out;

    (void)hipMemsetAsync(out, 0, sizeof(float), stream);
    wmse_kernel<<<kBlocks, kBlock, 0, stream>>>(predicted, target, out);
}

// Round 6
// 45.859 us; speedup vs baseline: 2.6417x; 2.6417x over previous
//
#include <hip/hip_runtime.h>

// WeightedMSELoss: loss = sum_i w(t_i) * (p_i - t_i)^2 / 31
// w(t) = 2^bin for t in (0.2*bin, 0.2*(bin+1)], bin in [0,5); else 0.
//
// R6: two-stage reduction. Stage 1: 2048 blocks, block-contiguous coalesced
// chunks, one partial sum per block stored to d_ws (NO atomics — same-address
// device atomics serialize ~8-10ns each; 2048 of them cost ~20us hidden tail).
// Stage 2: single block reduces the 2048 partials, writes out/31.

typedef float f4 __attribute__((ext_vector_type(4)));

constexpr int kN = 33554432;               // 2**25 floats per array
constexpr int kBlock = 256;
constexpr int kBlocks = 2048;
constexpr int kN4 = kN / 4;                // 2**23 float4
constexpr int kPerBlock = kN4 / kBlocks;   // 4096 float4 per block per array

__device__ __forceinline__ float contrib(float p, float t) {
    bool valid = (t > 0.0f) & (t <= 1.0f);
    int bin = (t > 0.2f) + (t > 0.4f) + (t > 0.6f) + (t > 0.8f);
    float d = p - t;
    float v = __builtin_ldexpf(d * d, bin);   // (p-t)^2 * 2^bin
    return valid ? v : 0.0f;
}

__device__ __forceinline__ float contrib4(f4 p, f4 t) {
    return contrib(p.x, t.x) + contrib(p.y, t.y) +
           contrib(p.z, t.z) + contrib(p.w, t.w);
}

__global__ __launch_bounds__(kBlock)
void wmse_stage1(const f4* __restrict__ p4,
                 const f4* __restrict__ t4,
                 float* __restrict__ partials) {
    int tid = threadIdx.x;
    int base = blockIdx.x * kPerBlock;

    float acc = 0.0f;
    #pragma unroll
    for (int it = 0; it < kPerBlock / (kBlock * 4); ++it) {   // 4 iters
        int i0 = base + it * kBlock * 4 + tid;
        f4 p0 = p4[i0];
        f4 p1 = p4[i0 + kBlock];
        f4 p2 = p4[i0 + 2 * kBlock];
        f4 p3 = p4[i0 + 3 * kBlock];
        f4 t0 = t4[i0];
        f4 t1 = t4[i0 + kBlock];
        f4 t2 = t4[i0 + 2 * kBlock];
        f4 t3 = t4[i0 + 3 * kBlock];
        acc += contrib4(p0, t0);
        acc += contrib4(p1, t1);
        acc += contrib4(p2, t2);
        acc += contrib4(p3, t3);
    }

    // wave-64 butterfly reduce
    #pragma unroll
    for (int off = 32; off > 0; off >>= 1)
        acc += __shfl_down(acc, off, 64);

    __shared__ float smem[kBlock / 64];
    int lane = tid & 63;
    int wid  = tid >> 6;
    if (lane == 0) smem[wid] = acc;
    __syncthreads();
    if (tid == 0) {
        float b = 0.0f;
        #pragma unroll
        for (int w = 0; w < kBlock / 64; ++w) b += smem[w];
        partials[blockIdx.x] = b;          // plain store, no atomic
    }
}

__global__ __launch_bounds__(512)
void wmse_stage2(const float* __restrict__ partials,
                 float* __restrict__ out) {
    int tid = threadIdx.x;
    float acc = 0.0f;
    #pragma unroll
    for (int i = 0; i < kBlocks / 512; ++i)    // 4 each
        acc += partials[tid + i * 512];

    #pragma unroll
    for (int off = 32; off > 0; off >>= 1)
        acc += __shfl_down(acc, off, 64);

    __shared__ float smem[512 / 64];
    int lane = tid & 63;
    int wid  = tid >> 6;
    if (lane == 0) smem[wid] = acc;
    __syncthreads();
    if (tid == 0) {
        float b = 0.0f;
        #pragma unroll
        for (int w = 0; w < 512 / 64; ++w) b += smem[w];
        out[0] = b * (1.0f / 31.0f);
    }
}

extern "C" void kernel_launch(void* const* d_in, const int* in_sizes, int n_in,
                              void* d_out, int out_size, void* d_ws, size_t ws_size,
                              hipStream_t stream) {
    const f4* predicted = (const f4*)d_in[0];
    const f4* target    = (const f4*)d_in[1];
    float* out = (float*)d_out;
    float* partials = (float*)d_ws;            // 2048 floats = 8 KB

    wmse_stage1<<<kBlocks, kBlock, 0, stream>>>(predicted, target, partials);
    wmse_stage2<<<1, 512, 0, stream>>>(partials, out);
}